// Round 1
// baseline (172.853 us; speedup 1.0000x reference)
//
#include <hip/hip_runtime.h>
#include <math.h>

// Problem: X[8192,64], Y[8192,64] fp32.
// d2[i][j] = |x_i|^2 + |y_j|^2 - 2 <x_i, y_j>
// out = mean_i sqrt(max(min_j d2, 0)) + mean_j sqrt(max(min_i d2, 0))
//
// min(sqrt(d2)) == sqrt(min(d2))  -> min in d2 domain, sqrt once at the end.
// d2 clamped >= 0 -> float bits are monotone as uint -> atomicMin on uint.

#define NROWS 8192
#define DDIM 64
#define INF_BITS 0x7F800000u

#define BI 128            // i-rows per block
#define BJ 128            // j-rows per chunk
#define CHUNKS 8          // j-chunks per block -> j-range 1024 per block
#define XS_STRIDE 68      // 64 + 4 pad, 16B-aligned rows, conflict-free b128
#define YS_STRIDE 36      // 32 + 4 pad (k staged in halves)

// ws layout (4-byte elements):
// [0,8192)       x2 (float)
// [8192,16384)   y2 (float)
// [16384,24576)  rowmin bits (uint)
// [24576,32768)  colmin bits (uint)

__global__ void prep_kernel(const float* __restrict__ X,
                            const float* __restrict__ Y,
                            float* __restrict__ ws,
                            float* __restrict__ out) {
  int tid = blockIdx.x * blockDim.x + threadIdx.x;  // 0..16383
  int row = tid & (NROWS - 1);
  const float* src = (tid < NROWS) ? X : Y;
  const float4* p = (const float4*)(src + row * DDIM);
  float s = 0.f;
#pragma unroll
  for (int c = 0; c < DDIM / 4; ++c) {
    float4 v = p[c];
    s = fmaf(v.x, v.x, s);
    s = fmaf(v.y, v.y, s);
    s = fmaf(v.z, v.z, s);
    s = fmaf(v.w, v.w, s);
  }
  ws[tid] = s;  // x2 then y2, contiguous
  ((unsigned int*)ws)[2 * NROWS + tid] = INF_BITS;  // rowmin+colmin init
  if (tid == 0) out[0] = 0.f;
}

__global__ __launch_bounds__(256, 2)
void mine_kernel(const float* __restrict__ X,
                 const float* __restrict__ Y,
                 float* __restrict__ ws) {
  __shared__ float Xs[BI * XS_STRIDE];      // full-k X tile
  __shared__ float Ys[BJ * YS_STRIDE];      // half-k Y tile
  __shared__ unsigned int cbuf[BJ];
  __shared__ unsigned int rbuf[BI];

  const float* x2g = ws;
  const float* y2g = ws + NROWS;
  unsigned int* rowmin_g = (unsigned int*)ws + 2 * NROWS;
  unsigned int* colmin_g = (unsigned int*)ws + 3 * NROWS;

  const int tid = threadIdx.x;
  const int tx = tid & 15;
  const int ty = tid >> 4;
  const int itile = blockIdx.x & 63;        // 64 i-tiles
  const int slice = blockIdx.x >> 6;        // 8 j-slices
  const int i0 = itile * BI;
  const int jbase = slice * (BJ * CHUNKS);

  // ---- stage X tile (once per block), coalesced float4 ----
#pragma unroll
  for (int p = 0; p < (BI * DDIM) / (256 * 4); ++p) {  // 8 passes
    int f = (p * 256 + tid) * 4;
    int r = f >> 6;
    int k = f & 63;
    *(float4*)(Xs + r * XS_STRIDE + k) = *(const float4*)(X + (i0 + r) * DDIM + k);
  }
  if (tid < BI) rbuf[tid] = INF_BITS;

  // per-thread x2 for its 8 interleaved i's (i = ty + 16*ii)
  float x2r[8];
#pragma unroll
  for (int ii = 0; ii < 8; ++ii) x2r[ii] = x2g[i0 + ty + 16 * ii];

  float rmin[8];
#pragma unroll
  for (int ii = 0; ii < 8; ++ii) rmin[ii] = INFINITY;

  for (int c = 0; c < CHUNKS; ++c) {
    const int j0 = jbase + c * BJ;

    float acc[8][8];
#pragma unroll
    for (int ii = 0; ii < 8; ++ii)
#pragma unroll
      for (int jj = 0; jj < 8; ++jj) acc[ii][jj] = 0.f;

    for (int kh = 0; kh < 2; ++kh) {
      __syncthreads();  // Ys free, prev cbuf consumed
      // stage Y half-tile (128 rows x 32 k), coalesced
#pragma unroll
      for (int p = 0; p < (BJ * 32) / (256 * 4); ++p) {  // 4 passes
        int f = (p * 256 + tid) * 4;
        int r = f >> 5;
        int k = f & 31;
        *(float4*)(Ys + r * YS_STRIDE + k) =
            *(const float4*)(Y + (j0 + r) * DDIM + kh * 32 + k);
      }
      if (kh == 0 && tid < BJ) cbuf[tid] = INF_BITS;
      __syncthreads();

      for (int k0 = 0; k0 < 32; k0 += 4) {
        float4 xf[8], yf[8];
#pragma unroll
        for (int ii = 0; ii < 8; ++ii)
          xf[ii] = *(const float4*)(Xs + (ty + 16 * ii) * XS_STRIDE + kh * 32 + k0);
#pragma unroll
        for (int jj = 0; jj < 8; ++jj)
          yf[jj] = *(const float4*)(Ys + (tx + 16 * jj) * YS_STRIDE + k0);
#pragma unroll
        for (int ii = 0; ii < 8; ++ii)
#pragma unroll
          for (int jj = 0; jj < 8; ++jj) {
            float a = acc[ii][jj];
            a = fmaf(xf[ii].x, yf[jj].x, a);
            a = fmaf(xf[ii].y, yf[jj].y, a);
            a = fmaf(xf[ii].z, yf[jj].z, a);
            a = fmaf(xf[ii].w, yf[jj].w, a);
            acc[ii][jj] = a;
          }
      }
    }

    // ---- epilogue: d2, row/col mins ----
    float y2r[8];
#pragma unroll
    for (int jj = 0; jj < 8; ++jj) y2r[jj] = y2g[j0 + tx + 16 * jj];

#pragma unroll
    for (int jj = 0; jj < 8; ++jj) {
      float cmin = INFINITY;
#pragma unroll
      for (int ii = 0; ii < 8; ++ii) {
        float d2 = fmaf(-2.f, acc[ii][jj], x2r[ii] + y2r[jj]);
        d2 = fmaxf(d2, 0.f);
        rmin[ii] = fminf(rmin[ii], d2);
        cmin = fminf(cmin, d2);
      }
      atomicMin(&cbuf[tx + 16 * jj], __float_as_uint(cmin));
    }
    __syncthreads();
    if (tid < BJ) atomicMin(&colmin_g[j0 + tid], cbuf[tid]);
  }

  // ---- rowmin: block-level then global ----
#pragma unroll
  for (int ii = 0; ii < 8; ++ii)
    atomicMin(&rbuf[ty + 16 * ii], __float_as_uint(rmin[ii]));
  __syncthreads();
  if (tid < BI) atomicMin(&rowmin_g[i0 + tid], rbuf[tid]);
}

__global__ void finish_kernel(const float* __restrict__ ws,
                              float* __restrict__ out) {
  int tid = blockIdx.x * blockDim.x + threadIdx.x;  // 0..16383
  const unsigned int* minb = (const unsigned int*)ws + 2 * NROWS;
  float v = sqrtf(__uint_as_float(minb[tid])) * (1.0f / 8192.0f);
#pragma unroll
  for (int off = 32; off > 0; off >>= 1) v += __shfl_down(v, off, 64);
  __shared__ float partial[4];
  if ((threadIdx.x & 63) == 0) partial[threadIdx.x >> 6] = v;
  __syncthreads();
  if (threadIdx.x == 0)
    atomicAdd(out, partial[0] + partial[1] + partial[2] + partial[3]);
}

extern "C" void kernel_launch(void* const* d_in, const int* in_sizes, int n_in,
                              void* d_out, int out_size, void* d_ws, size_t ws_size,
                              hipStream_t stream) {
  const float* X = (const float*)d_in[0];
  const float* Y = (const float*)d_in[1];
  float* out = (float*)d_out;
  float* ws = (float*)d_ws;

  prep_kernel<<<(2 * NROWS) / 256, 256, 0, stream>>>(X, Y, ws, out);
  mine_kernel<<<(NROWS / BI) * (NROWS / (BJ * CHUNKS)), 256, 0, stream>>>(X, Y, ws);
  finish_kernel<<<(2 * NROWS) / 256, 256, 0, stream>>>(ws, out);
}

// Round 2
// 112.525 us; speedup vs baseline: 1.5361x; 1.5361x over previous
//
#include <hip/hip_runtime.h>
#include <math.h>

// X[8192,64], Y[8192,64] fp32.
// d2[i][j] = x2_i + y2_j - 2<x_i,y_j>;  out = mean_i sqrt(min_j d2) + mean_j sqrt(min_i d2)
// Dot via bf16 MFMA 16x16x32 (error ~0.026 in d2, threshold 0.32 -> safe).
// Row path tracks min_j (y2_j - 2s); col path min_i (x2_i - 2s); x2/y2 + clamp + sqrt folded
// into finish. Values can be negative -> monotone uint key for atomicMin.

#define NROWS 8192
#define DDIM  64
#define BI 128
#define BJ 128
#define CHUNKS 4
#define LSTR 88            // bf16 elems/row: 176 B rows -> 16B-aligned b128, 12-mod-32 bank stagger
#define KEYINF 0xFFFFFFFFu

typedef __bf16 bf16_t;
typedef bf16_t bf16x8 __attribute__((ext_vector_type(8)));
typedef bf16_t bf16x4 __attribute__((ext_vector_type(4)));
typedef float  f32x4  __attribute__((ext_vector_type(4)));

__device__ __forceinline__ unsigned fkey(float f) {
  unsigned b = __float_as_uint(f);
  return b ^ ((unsigned)((int)b >> 31) | 0x80000000u);
}
__device__ __forceinline__ float funkey(unsigned k) {
  unsigned b = (k & 0x80000000u) ? (k ^ 0x80000000u) : ~k;
  return __uint_as_float(b);
}

// ws (4B elems): [0,8192) x2 | [8192,16384) y2 | [16384,24576) rowmin keys | [24576,32768) colmin keys

__global__ void prep_kernel(const float* __restrict__ X,
                            const float* __restrict__ Y,
                            float* __restrict__ ws,
                            float* __restrict__ out) {
  int tid = blockIdx.x * blockDim.x + threadIdx.x;  // 0..16383
  int row = tid & (NROWS - 1);
  const float* src = (tid < NROWS) ? X : Y;
  const float4* p = (const float4*)(src + row * DDIM);
  float s = 0.f;
#pragma unroll
  for (int c = 0; c < DDIM / 4; ++c) {
    float4 v = p[c];
    s = fmaf(v.x, v.x, s);
    s = fmaf(v.y, v.y, s);
    s = fmaf(v.z, v.z, s);
    s = fmaf(v.w, v.w, s);
  }
  ws[tid] = s;
  ((unsigned*)ws)[2 * NROWS + tid] = KEYINF;
  if (tid == 0) out[0] = 0.f;
}

__global__ __launch_bounds__(256, 3)
void mine_kernel(const float* __restrict__ X,
                 const float* __restrict__ Y,
                 float* __restrict__ ws) {
  __shared__ bf16_t Xs[BI * LSTR];
  __shared__ bf16_t Ys[BJ * LSTR];
  __shared__ unsigned cbuf[BJ];

  const float* x2g = ws;
  const float* y2g = ws + NROWS;
  unsigned* rowmin_g = (unsigned*)ws + 2 * NROWS;
  unsigned* colmin_g = (unsigned*)ws + 3 * NROWS;

  const int tid = threadIdx.x;
  const int L = tid & 63;
  const int w = tid >> 6;
  const int lr = L & 15;          // fragment row/col within 16-group
  const int q  = L >> 4;          // quad
  const int itile = blockIdx.x & 63;
  const int slice = blockIdx.x >> 6;
  const int i0 = itile * BI;
  const int jbase = slice * (BJ * CHUNKS);
  const int rgb = (w >> 1) * 64;  // wave's row offset in tile
  const int cgb = (w & 1) * 64;   // wave's col offset in tile

  // ---- stage X tile fp32->bf16, coalesced float4 passes ----
  const float4* Xg = (const float4*)X;
#pragma unroll
  for (int c = 0; c < 8; ++c) {
    int f = c * 256 + tid;
    int r = f >> 4, k4 = f & 15;
    float4 v = Xg[(i0 + r) * 16 + k4];
    bf16x4 h = {(bf16_t)v.x, (bf16_t)v.y, (bf16_t)v.z, (bf16_t)v.w};
    *(bf16x4*)&Xs[r * LSTR + k4 * 4] = h;
  }
  if (tid < BJ) cbuf[tid] = KEYINF;

  // per-lane x2 for wave's rows: row = rgb + a*16 + q*4 + p
  float x2r[4][4];
#pragma unroll
  for (int a = 0; a < 4; ++a)
#pragma unroll
    for (int p = 0; p < 4; ++p)
      x2r[a][p] = x2g[i0 + rgb + a * 16 + q * 4 + p];

  float rmin[4][4];
#pragma unroll
  for (int a = 0; a < 4; ++a)
#pragma unroll
    for (int p = 0; p < 4; ++p) rmin[a][p] = INFINITY;

  const float4* Yg = (const float4*)Y;
  for (int cc = 0; cc < CHUNKS; ++cc) {
    const int j0 = jbase + cc * BJ;
    // ---- stage Y chunk ----
#pragma unroll
    for (int c = 0; c < 8; ++c) {
      int f = c * 256 + tid;
      int r = f >> 4, k4 = f & 15;
      float4 v = Yg[(j0 + r) * 16 + k4];
      bf16x4 h = {(bf16_t)v.x, (bf16_t)v.y, (bf16_t)v.z, (bf16_t)v.w};
      *(bf16x4*)&Ys[r * LSTR + k4 * 4] = h;
    }
    __syncthreads();

    f32x4 acc[4][4];
#pragma unroll
    for (int a = 0; a < 4; ++a)
#pragma unroll
      for (int b = 0; b < 4; ++b) acc[a][b] = (f32x4){0.f, 0.f, 0.f, 0.f};

#pragma unroll
    for (int h = 0; h < 2; ++h) {
      bf16x8 Af[4], Bf[4];
#pragma unroll
      for (int a = 0; a < 4; ++a)
        Af[a] = *(const bf16x8*)&Xs[(rgb + a * 16 + lr) * LSTR + h * 32 + q * 8];
#pragma unroll
      for (int b = 0; b < 4; ++b)
        Bf[b] = *(const bf16x8*)&Ys[(cgb + b * 16 + lr) * LSTR + h * 32 + q * 8];
#pragma unroll
      for (int a = 0; a < 4; ++a)
#pragma unroll
        for (int b = 0; b < 4; ++b)
          acc[a][b] = __builtin_amdgcn_mfma_f32_16x16x32_bf16(Af[a], Bf[b], acc[a][b], 0, 0, 0);
    }

    // ---- epilogue: C/D layout col=lane&15, row=quad*4+reg ----
    float y2r[4];
#pragma unroll
    for (int b = 0; b < 4; ++b) y2r[b] = y2g[j0 + cgb + b * 16 + lr];
    float cmin0 = INFINITY, cmin1 = INFINITY, cmin2 = INFINITY, cmin3 = INFINITY;
#pragma unroll
    for (int a = 0; a < 4; ++a)
#pragma unroll
      for (int p = 0; p < 4; ++p) {
        float r0 = rmin[a][p];
        float x2v = x2r[a][p];
        {
          float s = acc[a][0][p];
          r0 = fminf(r0, fmaf(-2.f, s, y2r[0]));
          cmin0 = fminf(cmin0, fmaf(-2.f, s, x2v));
        }
        {
          float s = acc[a][1][p];
          r0 = fminf(r0, fmaf(-2.f, s, y2r[1]));
          cmin1 = fminf(cmin1, fmaf(-2.f, s, x2v));
        }
        {
          float s = acc[a][2][p];
          r0 = fminf(r0, fmaf(-2.f, s, y2r[2]));
          cmin2 = fminf(cmin2, fmaf(-2.f, s, x2v));
        }
        {
          float s = acc[a][3][p];
          r0 = fminf(r0, fmaf(-2.f, s, y2r[3]));
          cmin3 = fminf(cmin3, fmaf(-2.f, s, x2v));
        }
        rmin[a][p] = r0;
      }
    // colmin: reduce over quads (rows), then lane-quad q owns col group b=q
    cmin0 = fminf(cmin0, __shfl_xor(cmin0, 16, 64));
    cmin0 = fminf(cmin0, __shfl_xor(cmin0, 32, 64));
    cmin1 = fminf(cmin1, __shfl_xor(cmin1, 16, 64));
    cmin1 = fminf(cmin1, __shfl_xor(cmin1, 32, 64));
    cmin2 = fminf(cmin2, __shfl_xor(cmin2, 16, 64));
    cmin2 = fminf(cmin2, __shfl_xor(cmin2, 32, 64));
    cmin3 = fminf(cmin3, __shfl_xor(cmin3, 16, 64));
    cmin3 = fminf(cmin3, __shfl_xor(cmin3, 32, 64));
    {
      float v = cmin0;
      if (q == 1) v = cmin1;
      else if (q == 2) v = cmin2;
      else if (q == 3) v = cmin3;
      atomicMin(&cbuf[cgb + q * 16 + lr], fkey(v));
    }
    __syncthreads();
    if (tid < BJ) {
      unsigned k = cbuf[tid];
      atomicMin(&colmin_g[j0 + tid], k);
      cbuf[tid] = KEYINF;
    }
  }

  // ---- rowmin: reduce over the 16 cols (lanes), write ----
#pragma unroll
  for (int a = 0; a < 4; ++a)
#pragma unroll
    for (int p = 0; p < 4; ++p) {
      float v = rmin[a][p];
      v = fminf(v, __shfl_xor(v, 1, 64));
      v = fminf(v, __shfl_xor(v, 2, 64));
      v = fminf(v, __shfl_xor(v, 4, 64));
      v = fminf(v, __shfl_xor(v, 8, 64));
      if (lr == 0)
        atomicMin(&rowmin_g[i0 + rgb + a * 16 + q * 4 + p], fkey(v));
    }
}

__global__ void finish_kernel(const float* __restrict__ ws,
                              float* __restrict__ out) {
  int tid = blockIdx.x * blockDim.x + threadIdx.x;  // 0..16383
  const unsigned* keys = (const unsigned*)ws + 2 * NROWS;
  float d2 = ws[tid] + funkey(keys[tid]);   // x2_i + rmin  or  y2_j + cmin
  float v = sqrtf(fmaxf(d2, 0.f)) * (1.0f / 8192.0f);
#pragma unroll
  for (int off = 32; off > 0; off >>= 1) v += __shfl_down(v, off, 64);
  __shared__ float partial[4];
  if ((threadIdx.x & 63) == 0) partial[threadIdx.x >> 6] = v;
  __syncthreads();
  if (threadIdx.x == 0)
    atomicAdd(out, partial[0] + partial[1] + partial[2] + partial[3]);
}

extern "C" void kernel_launch(void* const* d_in, const int* in_sizes, int n_in,
                              void* d_out, int out_size, void* d_ws, size_t ws_size,
                              hipStream_t stream) {
  const float* X = (const float*)d_in[0];
  const float* Y = (const float*)d_in[1];
  float* out = (float*)d_out;
  float* ws = (float*)d_ws;

  prep_kernel<<<(2 * NROWS) / 256, 256, 0, stream>>>(X, Y, ws, out);
  mine_kernel<<<(NROWS / BI) * (NROWS / (BJ * CHUNKS)), 256, 0, stream>>>(X, Y, ws);
  finish_kernel<<<(2 * NROWS) / 256, 256, 0, stream>>>(ws, out);
}